// Round 10
// baseline (57.249 us; speedup 1.0000x reference)
//
#include <hip/hip_runtime.h>
#include <stdint.h>

#define BATCH 16
#define NPTS 4096
#define DIM 384
#define NTOK (2*NPTS)
#define F4PT (DIM/4)   // 96 float4 groups per token

typedef unsigned long long u64;

// Morton spread: place bit b of an 8-bit value at position 3b.
__device__ __forceinline__ uint32_t spread3(uint32_t x) {
    x = (x | (x << 8)) & 0x00F00Fu;
    x = (x | (x << 4)) & 0x0C30C3u;
    x = (x | (x << 2)) & 0x249249u;
    return x;
}

// Exact port of the reference Skilling transform (bits=8, ndim=3).
__device__ __forceinline__ uint32_t hilbert3(uint32_t x0, uint32_t x1, uint32_t x2) {
    #pragma unroll
    for (uint32_t q = 128; q > 1; q >>= 1) {
        uint32_t pm = q - 1;
        if (x0 & q) x0 ^= pm;
        uint32_t t = (x0 ^ x1) & pm;
        if (x1 & q) { x0 ^= pm; } else { x0 ^= t; x1 ^= t; }
        t = (x0 ^ x2) & pm;
        if (x2 & q) { x0 ^= pm; } else { x0 ^= t; x2 ^= t; }
    }
    x1 ^= x0;
    x2 ^= x1;
    uint32_t t = 0;
    #pragma unroll
    for (uint32_t q = 128; q > 1; q >>= 1) { if (x2 & q) t ^= (q - 1); }
    x0 ^= t; x1 ^= t; x2 ^= t;
    return (spread3(x0) << 2) | (spread3(x1) << 1) | spread3(x2);
}

// K0: one block per batch. Reads the batch's 4096 points ONCE, writes
// mm[b*8+{0..5}] = {minx,miny,minz,spanx,spany,spanz}.
__global__ __launch_bounds__(256) void minmax_kernel(const float* __restrict__ x,
                                                     float* __restrict__ mm) {
    const int b = blockIdx.x;
    const int t = threadIdx.x;
    __shared__ float red[4 * 6];
    const float4* xb4 = (const float4*)(x + (size_t)b * NPTS * 3);

    float mnx = 1e30f, mny = 1e30f, mnz = 1e30f;
    float mxx = -1e30f, mxy = -1e30f, mxz = -1e30f;
    #pragma unroll
    for (int g = 0; g < 4; ++g) {
        float4 q0 = xb4[12*t + 3*g + 0];
        float4 q1 = xb4[12*t + 3*g + 1];
        float4 q2 = xb4[12*t + 3*g + 2];
        float px[4] = {q0.x, q0.w, q1.z, q2.y};
        float py[4] = {q0.y, q1.x, q1.w, q2.z};
        float pz[4] = {q0.z, q1.y, q2.x, q2.w};
        #pragma unroll
        for (int r = 0; r < 4; ++r) {
            mnx = fminf(mnx, px[r]); mxx = fmaxf(mxx, px[r]);
            mny = fminf(mny, py[r]); mxy = fmaxf(mxy, py[r]);
            mnz = fminf(mnz, pz[r]); mxz = fmaxf(mxz, pz[r]);
        }
    }
    #pragma unroll
    for (int off = 32; off > 0; off >>= 1) {
        mnx = fminf(mnx, __shfl_xor(mnx, off));
        mny = fminf(mny, __shfl_xor(mny, off));
        mnz = fminf(mnz, __shfl_xor(mnz, off));
        mxx = fmaxf(mxx, __shfl_xor(mxx, off));
        mxy = fmaxf(mxy, __shfl_xor(mxy, off));
        mxz = fmaxf(mxz, __shfl_xor(mxz, off));
    }
    int wave = t >> 6;
    if ((t & 63) == 0) {
        red[wave*6+0] = mnx; red[wave*6+1] = mny; red[wave*6+2] = mnz;
        red[wave*6+3] = mxx; red[wave*6+4] = mxy; red[wave*6+5] = mxz;
    }
    __syncthreads();
    if (t == 0) {
        for (int w = 1; w < 4; ++w) {
            mnx = fminf(mnx, red[w*6+0]); mny = fminf(mny, red[w*6+1]);
            mnz = fminf(mnz, red[w*6+2]); mxx = fmaxf(mxx, red[w*6+3]);
            mxy = fmaxf(mxy, red[w*6+4]); mxz = fmaxf(mxz, red[w*6+5]);
        }
        mm[b*8+0] = mnx; mm[b*8+1] = mny; mm[b*8+2] = mnz;
        mm[b*8+3] = fmaxf(mxx - mnx, 1e-6f);
        mm[b*8+4] = fmaxf(mxy - mny, 1e-6f);
        mm[b*8+5] = fmaxf(mxz - mnz, 1e-6f);
    }
}

// K1: block = (b, v, octant). 512 threads, 1 element each. Reads mm + own
// 512 points only. 6-pass 4-bit stable radix sort of the octant, writes
// sorted run to kws. Key = (code<<12)|global_idx -> all keys distinct.
// Per pass: rank -> B1 -> scan -> B2 -> scatter -> B3; per-pass hist regions
// pre-zeroed once (no re-clear barrier).
__global__ __launch_bounds__(512) void order_radix_o(const float* __restrict__ x,
                                                     const float* __restrict__ mm,
                                                     u64* __restrict__ kws) {
    const int bi = blockIdx.x;
    const int b = bi >> 4;
    const int v = (bi >> 3) & 1;
    const int oct = bi & 7;
    const int t = threadIdx.x;
    const int lane = t & 63;
    const int w = t >> 6;          // 8 waves

    __shared__ u64 skey[512];             // 4 KB
    __shared__ uint32_t hist[6 * 128];    // per-pass regions hist[p][d*8+w], 3 KB
    __shared__ uint32_t baseArr[16];

    // Zero all per-pass hist regions up front.
    hist[t] = 0u;                       // entries 0..511
    if (t < 256) hist[512 + t] = 0u;    // entries 512..767

    const float mnx = mm[b*8+0], mny = mm[b*8+1], mnz = mm[b*8+2];
    const float spx = mm[b*8+3], spy = mm[b*8+4], spz = mm[b*8+5];

    const float* xb = x + (size_t)b * NPTS * 3;

    // Code own point n0 = oct*512 + t.
    u64 key;
    {
        const int n0 = (oct << 9) + t;
        float cx = xb[3*n0+0], cy = xb[3*n0+1], cz = xb[3*n0+2];
        float gx = fminf(fmaxf(((cx - mnx) / spx) * 255.0f, 0.0f), 255.0f);
        float gy = fminf(fmaxf(((cy - mny) / spy) * 255.0f, 0.0f), 255.0f);
        float gz = fminf(fmaxf(((cz - mnz) / spz) * 255.0f, 0.0f), 255.0f);
        uint32_t ix = (uint32_t)(int)gx;
        uint32_t iy = (uint32_t)(int)gy;
        uint32_t iz = (uint32_t)(int)gz;
        uint32_t a0 = v ? iz : ix;
        uint32_t a2 = v ? ix : iz;
        uint32_t code = hilbert3(a0, iy, a2);
        key = ((u64)code << 12) | (u64)n0;
    }
    __syncthreads();   // hist zeroing visible

    const u64 below_mask = (1ull << lane) - 1ull;
    u64* segk = kws + (((b << 1) | v) << 12);

    // 6 stable radix passes, 4-bit digits over key bits [12, 36).
    #pragma unroll
    for (int p = 0; p < 6; ++p) {
        const int sh = 12 + 4 * p;
        uint32_t* histp = hist + p * 128;

        unsigned d = (unsigned)(key >> sh) & 15u;
        u64 m = ~0ull;
        #pragma unroll
        for (int bit = 0; bit < 4; ++bit) {
            u64 bal = __ballot((int)((d >> bit) & 1u));
            m &= ((d >> bit) & 1u) ? bal : ~bal;
        }
        unsigned rk = (unsigned)__popcll(m & below_mask);
        if (rk == 0u)
            histp[d * 8 + w] = (unsigned)__popcll(m);
        __syncthreads();   // B1

        // Threads 0..15: serial scan of bin t's 8 slots + 16-lane shfl scan
        // of bin totals -> baseArr.
        if (t < 16) {
            unsigned running = 0;
            #pragma unroll
            for (int s = 0; s < 8; ++s) {
                unsigned hv = histp[t * 8 + s];
                histp[t * 8 + s] = running;
                running += hv;
            }
            unsigned tv = running;
            #pragma unroll
            for (int off = 1; off < 16; off <<= 1) {
                unsigned nv = __shfl_up(tv, off);
                if (lane >= off) tv += nv;
            }
            baseArr[t] = tv - running;
        }
        __syncthreads();   // B2

        unsigned pos = baseArr[d] + histp[d * 8 + w] + rk;

        if (p < 5) {
            skey[pos] = key;
            __syncthreads();   // B3
            key = skey[t];
        } else {
            segk[(oct << 9) + pos] = key;
        }
    }
}

// K2: block = (b, v, octant). Rank = own position + count-less in each of the
// other 7 sorted runs (binary search in LDS). Keys distinct, so the result is
// exactly the stable argsort. Writes order[rank] = idx.
__global__ __launch_bounds__(512) void order_merge_o(const u64* __restrict__ kws,
                                                     int* __restrict__ order) {
    const int bi = blockIdx.x;
    const int b = bi >> 4;
    const int v = (bi >> 3) & 1;
    const int oct = bi & 7;
    const int t = threadIdx.x;

    __shared__ u64 sk[7 * 512];   // 28 KB

    const u64* segk = kws + (((b << 1) | v) << 12);
    u64 k = segk[(oct << 9) + t];

    #pragma unroll
    for (int j = 0; j < 7; ++j) {
        int oq = j + (j >= oct ? 1 : 0);
        sk[j * 512 + t] = segk[(oq << 9) + t];
    }
    __syncthreads();

    int rank = t;
    #pragma unroll
    for (int j = 0; j < 7; ++j) {
        const u64* s = &sk[j * 512];
        int c = 0;
        #pragma unroll
        for (int step = 512; step >= 1; step >>= 1) {
            if (c + step <= 512 && s[c + step - 1] < k) c += step;
        }
        rank += c;
    }

    order[(((b << 1) | v) << 12) + rank] = (int)(k & 0xFFFull);
}

// Grid-stride over float4 output groups. Coeffs staged in LDS.
__global__ __launch_bounds__(256) void token_kernel(const float* __restrict__ x,
                                                    const float* __restrict__ W,
                                                    const float* __restrict__ bias,
                                                    const float* __restrict__ gamma,
                                                    const float* __restrict__ beta,
                                                    const int* __restrict__ order,
                                                    float* __restrict__ out) {
    __shared__ __align__(16) float sW0[2][DIM];
    __shared__ __align__(16) float sW1[2][DIM];
    __shared__ __align__(16) float sW2[2][DIM];
    __shared__ __align__(16) float sC[2][DIM];
    for (int i = threadIdx.x; i < 2 * DIM; i += 256) {
        int v = i / DIM;
        int d = i - v * DIM;
        float g = gamma[i];
        sW0[v][d] = g * W[d*3+0];
        sW1[v][d] = g * W[d*3+1];
        sW2[v][d] = g * W[d*3+2];
        sC[v][d]  = g * bias[d] + beta[i];
    }
    __syncthreads();

    const int total = BATCH * NTOK * F4PT;   // 12,582,912
    const int stride = gridDim.x * blockDim.x;
    for (int g4 = blockIdx.x * blockDim.x + threadIdx.x; g4 < total; g4 += stride) {
        int token = g4 / F4PT;
        int grp = g4 - token * F4PT;
        int b = token >> 13;           // / NTOK
        int nn = token & (NTOK - 1);
        int v = nn >> 12;              // / NPTS
        int n = nn & (NPTS - 1);
        int idx = order[(((b << 1) | v) << 12) + n];
        const float* p = x + (size_t)(b * NPTS + idx) * 3;
        float px = p[0], py = p[1], pz = p[2];
        int d0 = grp << 2;
        float4 w0 = *(const float4*)&sW0[v][d0];
        float4 w1 = *(const float4*)&sW1[v][d0];
        float4 w2 = *(const float4*)&sW2[v][d0];
        float4 c  = *(const float4*)&sC[v][d0];
        float4 o;
        o.x = px*w0.x + py*w1.x + pz*w2.x + c.x;
        o.y = px*w0.y + py*w1.y + pz*w2.y + c.y;
        o.z = px*w0.z + py*w1.z + pz*w2.z + c.z;
        o.w = px*w0.w + py*w1.w + pz*w2.w + c.w;
        reinterpret_cast<float4*>(out)[g4] = o;
    }
}

extern "C" void kernel_launch(void* const* d_in, const int* in_sizes, int n_in,
                              void* d_out, int out_size, void* d_ws, size_t ws_size,
                              hipStream_t stream) {
    const float* x     = (const float*)d_in[0];
    const float* W     = (const float*)d_in[1];
    const float* bias  = (const float*)d_in[2];
    const float* gamma = (const float*)d_in[3];
    const float* beta  = (const float*)d_in[4];

    u64* kws   = (u64*)d_ws;                    // 32*4096*8 = 1 MB
    int* order = (int*)(kws + 32 * 4096);       // 512 KB
    float* mm  = (float*)(order + 32 * 4096);   // 16*8 floats

    hipLaunchKernelGGL(minmax_kernel, dim3(BATCH),      dim3(256), 0, stream, x, mm);
    hipLaunchKernelGGL(order_radix_o, dim3(BATCH * 16), dim3(512), 0, stream, x, mm, kws);
    hipLaunchKernelGGL(order_merge_o, dim3(BATCH * 16), dim3(512), 0, stream, kws, order);
    hipLaunchKernelGGL(token_kernel,  dim3(2048),       dim3(256), 0, stream,
                       x, W, bias, gamma, beta, order, (float*)d_out);
}

// Round 11
// 50.780 us; speedup vs baseline: 1.1274x; 1.1274x over previous
//
#include <hip/hip_runtime.h>
#include <stdint.h>

#define BATCH 16
#define NPTS 4096
#define DIM 384
#define NTOK (2*NPTS)
#define F4PT (DIM/4)   // 96 float4 groups per token

typedef unsigned long long u64;

// Morton spread: place bit b of an 8-bit value at position 3b.
__device__ __forceinline__ uint32_t spread3(uint32_t x) {
    x = (x | (x << 8)) & 0x00F00Fu;
    x = (x | (x << 4)) & 0x0C30C3u;
    x = (x | (x << 2)) & 0x249249u;
    return x;
}

// Exact port of the reference Skilling transform (bits=8, ndim=3).
__device__ __forceinline__ uint32_t hilbert3(uint32_t x0, uint32_t x1, uint32_t x2) {
    #pragma unroll
    for (uint32_t q = 128; q > 1; q >>= 1) {
        uint32_t pm = q - 1;
        if (x0 & q) x0 ^= pm;
        uint32_t t = (x0 ^ x1) & pm;
        if (x1 & q) { x0 ^= pm; } else { x0 ^= t; x1 ^= t; }
        t = (x0 ^ x2) & pm;
        if (x2 & q) { x0 ^= pm; } else { x0 ^= t; x2 ^= t; }
    }
    x1 ^= x0;
    x2 ^= x1;
    uint32_t t = 0;
    #pragma unroll
    for (uint32_t q = 128; q > 1; q >>= 1) { if (x2 & q) t ^= (q - 1); }
    x0 ^= t; x1 ^= t; x2 ^= t;
    return (spread3(x0) << 2) | (spread3(x1) << 1) | spread3(x2);
}

// K1: block = (b, v, octant). 512 threads, 1 element each. Batch minmax
// (vectorized, redundant per block, L2/L3-hot), code own point, 6-pass 4-bit
// stable radix sort of the 512-element octant, write sorted run to kws.
// Key = (code<<12)|global_idx -> all keys distinct.
__global__ __launch_bounds__(512) void order_radix_o(const float* __restrict__ x,
                                                     u64* __restrict__ kws) {
    const int bi = blockIdx.x;
    const int b = bi >> 4;
    const int v = (bi >> 3) & 1;
    const int oct = bi & 7;
    const int t = threadIdx.x;
    const int lane = t & 63;
    const int w = t >> 6;          // 8 waves

    __shared__ u64 skey[512];             // 4 KB
    __shared__ uint32_t hist[6 * 128];    // per-pass regions hist[p][d*8+w], 3 KB
    __shared__ uint32_t baseArr[16];
    __shared__ float red[8 * 6];

    const float* xb = x + (size_t)b * NPTS * 3;
    const float4* xb4 = (const float4*)xb;

    // --- vectorized batch min/max: 8 points/thread ---
    float mnx = 1e30f, mny = 1e30f, mnz = 1e30f;
    float mxx = -1e30f, mxy = -1e30f, mxz = -1e30f;
    #pragma unroll
    for (int h = 0; h < 2; ++h) {
        float4 q0 = xb4[h * 1536 + 3 * t + 0];
        float4 q1 = xb4[h * 1536 + 3 * t + 1];
        float4 q2 = xb4[h * 1536 + 3 * t + 2];
        float px[4] = {q0.x, q0.w, q1.z, q2.y};
        float py[4] = {q0.y, q1.x, q1.w, q2.z};
        float pz[4] = {q0.z, q1.y, q2.x, q2.w};
        #pragma unroll
        for (int r = 0; r < 4; ++r) {
            mnx = fminf(mnx, px[r]); mxx = fmaxf(mxx, px[r]);
            mny = fminf(mny, py[r]); mxy = fmaxf(mxy, py[r]);
            mnz = fminf(mnz, pz[r]); mxz = fmaxf(mxz, pz[r]);
        }
    }
    #pragma unroll
    for (int off = 32; off > 0; off >>= 1) {
        mnx = fminf(mnx, __shfl_xor(mnx, off));
        mny = fminf(mny, __shfl_xor(mny, off));
        mnz = fminf(mnz, __shfl_xor(mnz, off));
        mxx = fmaxf(mxx, __shfl_xor(mxx, off));
        mxy = fmaxf(mxy, __shfl_xor(mxy, off));
        mxz = fmaxf(mxz, __shfl_xor(mxz, off));
    }
    if (lane == 0) {
        red[w*6+0] = mnx; red[w*6+1] = mny; red[w*6+2] = mnz;
        red[w*6+3] = mxx; red[w*6+4] = mxy; red[w*6+5] = mxz;
    }
    // Zero all per-pass hist regions while the reduction settles.
    hist[t] = 0u;
    if (t < 256) hist[512 + t] = 0u;
    __syncthreads();
    if (t == 0) {
        for (int ww = 1; ww < 8; ++ww) {
            mnx = fminf(mnx, red[ww*6+0]); mny = fminf(mny, red[ww*6+1]);
            mnz = fminf(mnz, red[ww*6+2]); mxx = fmaxf(mxx, red[ww*6+3]);
            mxy = fmaxf(mxy, red[ww*6+4]); mxz = fmaxf(mxz, red[ww*6+5]);
        }
        red[0] = mnx; red[1] = mny; red[2] = mnz;
        red[3] = fmaxf(mxx - mnx, 1e-6f);
        red[4] = fmaxf(mxy - mny, 1e-6f);
        red[5] = fmaxf(mxz - mnz, 1e-6f);
    }
    __syncthreads();
    mnx = red[0]; mny = red[1]; mnz = red[2];
    const float spx = red[3], spy = red[4], spz = red[5];

    // Code own point n0 = oct*512 + t.
    u64 key;
    {
        const int n0 = (oct << 9) + t;
        float cx = xb[3*n0+0], cy = xb[3*n0+1], cz = xb[3*n0+2];
        float gx = fminf(fmaxf(((cx - mnx) / spx) * 255.0f, 0.0f), 255.0f);
        float gy = fminf(fmaxf(((cy - mny) / spy) * 255.0f, 0.0f), 255.0f);
        float gz = fminf(fmaxf(((cz - mnz) / spz) * 255.0f, 0.0f), 255.0f);
        uint32_t ix = (uint32_t)(int)gx;
        uint32_t iy = (uint32_t)(int)gy;
        uint32_t iz = (uint32_t)(int)gz;
        uint32_t a0 = v ? iz : ix;
        uint32_t a2 = v ? ix : iz;
        uint32_t code = hilbert3(a0, iy, a2);
        key = ((u64)code << 12) | (u64)n0;
    }

    const u64 below_mask = (1ull << lane) - 1ull;
    u64* segk = kws + (((b << 1) | v) << 12);

    // 6 stable radix passes, 4-bit digits over key bits [12, 36).
    #pragma unroll
    for (int p = 0; p < 6; ++p) {
        const int sh = 12 + 4 * p;
        uint32_t* histp = hist + p * 128;

        unsigned d = (unsigned)(key >> sh) & 15u;
        u64 m = ~0ull;
        #pragma unroll
        for (int bit = 0; bit < 4; ++bit) {
            u64 bal = __ballot((int)((d >> bit) & 1u));
            m &= ((d >> bit) & 1u) ? bal : ~bal;
        }
        unsigned rk = (unsigned)__popcll(m & below_mask);
        if (rk == 0u)
            histp[d * 8 + w] = (unsigned)__popcll(m);
        __syncthreads();   // B1

        if (t < 16) {
            unsigned running = 0;
            #pragma unroll
            for (int s = 0; s < 8; ++s) {
                unsigned hv = histp[t * 8 + s];
                histp[t * 8 + s] = running;
                running += hv;
            }
            unsigned tv = running;
            #pragma unroll
            for (int off = 1; off < 16; off <<= 1) {
                unsigned nv = __shfl_up(tv, off);
                if (lane >= off) tv += nv;
            }
            baseArr[t] = tv - running;
        }
        __syncthreads();   // B2

        unsigned pos = baseArr[d] + histp[d * 8 + w] + rk;

        if (p < 5) {
            skey[pos] = key;
            __syncthreads();   // B3
            key = skey[t];
        } else {
            segk[(oct << 9) + pos] = key;
        }
    }
}

// K2: block = (b, v, octant). Loads all 8 sorted runs, computes global rank of
// each own-run element (7 interleaved binary searches; keys distinct => exact
// stable argsort), gathers point coords, then directly emits the 512 output
// token rows: out[b][v*4096 + rank][:] = gamma*(W@p + bias) + beta.
__global__ __launch_bounds__(512) void merge_emit_kernel(const float* __restrict__ x,
                                                         const float* __restrict__ W,
                                                         const float* __restrict__ bias,
                                                         const float* __restrict__ gamma,
                                                         const float* __restrict__ beta,
                                                         const u64* __restrict__ kws,
                                                         float4* __restrict__ out4) {
    const int bi = blockIdx.x;
    const int b = bi >> 4;
    const int v = (bi >> 3) & 1;
    const int oct = bi & 7;
    const int t = threadIdx.x;

    __shared__ u64 runs[8 * 512];                       // 32 KB
    __shared__ __align__(16) float sw0[DIM], sw1[DIM], sw2[DIM], sc[DIM];  // 6 KB
    __shared__ float cxs[512], cys[512], czs[512];      // 6 KB
    __shared__ int rnk[512];                            // 2 KB

    // Coeffs (fused gamma/beta), one v per block.
    if (t < DIM) {
        float g = gamma[v * DIM + t];
        sw0[t] = g * W[t*3+0];
        sw1[t] = g * W[t*3+1];
        sw2[t] = g * W[t*3+2];
        sc[t]  = g * bias[t] + beta[v * DIM + t];
    }

    // Load the 8 sorted runs for this (b, v).
    const u64* segk = kws + (((b << 1) | v) << 12);
    #pragma unroll
    for (int j = 0; j < 8; ++j)
        runs[(j << 9) + t] = segk[(j << 9) + t];
    __syncthreads();

    // Rank = own position + count-less in the other 7 runs.
    u64 k = runs[(oct << 9) + t];
    int base7[7], c[7];
    #pragma unroll
    for (int j = 0; j < 7; ++j) {
        base7[j] = (j + (j >= oct ? 1 : 0)) << 9;
        c[j] = 0;
    }
    // Step-outer: the 7 dependent LDS chains interleave.
    #pragma unroll
    for (int step = 512; step >= 1; step >>= 1) {
        #pragma unroll
        for (int j = 0; j < 7; ++j) {
            if (c[j] + step <= 512 && runs[base7[j] + c[j] + step - 1] < k)
                c[j] += step;
        }
    }
    int rank = t;
    #pragma unroll
    for (int j = 0; j < 7; ++j) rank += c[j];

    // Gather own point's coords.
    {
        int idx = (int)(k & 0xFFFull);
        const float* p = x + (size_t)b * NPTS * 3 + idx * 3;
        cxs[t] = p[0]; cys[t] = p[1]; czs[t] = p[2];
        rnk[t] = rank;
    }
    __syncthreads();

    // Emit 512 rows x 96 float4 groups. i/96 mapping: a wave covers <=2 rows,
    // contiguous within each row -> coalesced ~1.5 KB segments.
    const int tokbase = (b << 13) + (v << 12);
    for (int i = t; i < 512 * F4PT; i += 512) {
        int r = i / F4PT;
        int g = i - r * F4PT;
        float pxr = cxs[r], pyr = cys[r], pzr = czs[r];
        int d0 = g << 2;
        float4 w0 = *(const float4*)&sw0[d0];
        float4 w1 = *(const float4*)&sw1[d0];
        float4 w2 = *(const float4*)&sw2[d0];
        float4 cc = *(const float4*)&sc[d0];
        float4 o;
        o.x = pxr*w0.x + pyr*w1.x + pzr*w2.x + cc.x;
        o.y = pxr*w0.y + pyr*w1.y + pzr*w2.y + cc.y;
        o.z = pxr*w0.z + pyr*w1.z + pzr*w2.z + cc.z;
        o.w = pxr*w0.w + pyr*w1.w + pzr*w2.w + cc.w;
        out4[(size_t)(tokbase + rnk[r]) * F4PT + g] = o;
    }
}

extern "C" void kernel_launch(void* const* d_in, const int* in_sizes, int n_in,
                              void* d_out, int out_size, void* d_ws, size_t ws_size,
                              hipStream_t stream) {
    const float* x     = (const float*)d_in[0];
    const float* W     = (const float*)d_in[1];
    const float* bias  = (const float*)d_in[2];
    const float* gamma = (const float*)d_in[3];
    const float* beta  = (const float*)d_in[4];

    u64* kws = (u64*)d_ws;   // 32*4096*8 = 1 MB

    hipLaunchKernelGGL(order_radix_o,     dim3(BATCH * 16), dim3(512), 0, stream, x, kws);
    hipLaunchKernelGGL(merge_emit_kernel, dim3(BATCH * 16), dim3(512), 0, stream,
                       x, W, bias, gamma, beta, kws, (float4*)d_out);
}